// Round 1
// 429.404 us; speedup vs baseline: 1.0110x; 1.0110x over previous
//
#include <hip/hip_runtime.h>

// Problem constants (fixed by the reference file).
#define D_DIM    512
#define B_DIM    64
#define L_DIM    2048
#define NBLK1    256       // phase-1 blocks; 1/CU (128 KiB LDS)
#define THREADS1 512
#define XSZ      (B_DIM * D_DIM)          // 32768 floats per partial

// Native clang vector type (required by __builtin_nontemporal_store).
typedef float f32x4 __attribute__((ext_vector_type(4)));

// ---------------------------------------------------------------------------
// Phase 1: per-block segment-sum into a [B, D] LDS accumulator.
// Thread tid exclusively owns column tid, so plain ds_read / v_add / ds_write
// is race-free. Duplicate-position nodes (ia==ib) handled by the a-then-b
// write order with 2v on the second write.
//
// R6 change: positions are read at WAVE-UNIFORM addresses straight from
// global memory (no LDS pos[] staging). The loop counter and block offset are
// uniform, tp is const __restrict__, so the compiler emits s_load_dwordx*
// through the scalar cache -- zero LDS-pipe cost. This cuts LDS wave-ops per
// node-CU from 48 (32 acc RMW + 16 pos reads) to the 32-op RMW floor,
// ~280 -> ~186 cyc/node, pushing phase 1 from LDS-issue-bound to
// HBM-read-bound (~200 cyc/node).
// chunk is rounded to a multiple of 8 so tpp is 64 B-aligned (x16 s_loads)
// and every block's n is a multiple of 8 (tail loop never runs).
// ---------------------------------------------------------------------------
__device__ __forceinline__ void rmw2(float* acc, int ia, int ib, float v) {
    float ra = acc[ia];
    float rb = acc[ib];
    float addb = (ia == ib) ? (v + v) : v;
    acc[ia] = ra + v;      // if ia==ib this write is superseded by the next
    acc[ib] = rb + addb;
}

__global__ __launch_bounds__(THREADS1)
void seg_sum_kernel(const float* __restrict__ g, const int* __restrict__ tp,
                    float* __restrict__ dst, int N, int chunk, int use_atomic) {
    __shared__ float acc[XSZ];             // 128 KiB -> 1 block/CU
    const int tid = threadIdx.x;

    // float4 zero-init (crosses column ownership -> one barrier after).
    f32x4* a4i = (f32x4*)acc;
    for (int i = tid; i < XSZ / 4; i += THREADS1) a4i[i] = (f32x4)0.0f;
    __syncthreads();

    int start = blockIdx.x * chunk;
    int end   = start + chunk; if (end > N) end = N;
    int n     = end - start;

    const float* gp  = g  + (size_t)start * D_DIM + tid;
    const int*   tpp = tp + 2 * (size_t)start;   // uniform base, 64 B-aligned

    int i = 0;
    for (; i + 8 <= n; i += 8) {
        // 16 consecutive uniform int loads -> scalar cache (s_load), not LDS.
        int p0  = tpp[2*i+ 0], p1  = tpp[2*i+ 1], p2  = tpp[2*i+ 2], p3  = tpp[2*i+ 3];
        int p4  = tpp[2*i+ 4], p5  = tpp[2*i+ 5], p6  = tpp[2*i+ 6], p7  = tpp[2*i+ 7];
        int p8  = tpp[2*i+ 8], p9  = tpp[2*i+ 9], p10 = tpp[2*i+10], p11 = tpp[2*i+11];
        int p12 = tpp[2*i+12], p13 = tpp[2*i+13], p14 = tpp[2*i+14], p15 = tpp[2*i+15];
        // 8 independent 2 KB/block-row loads in flight per wave.
        float v0 = gp[(size_t)(i + 0) * D_DIM];
        float v1 = gp[(size_t)(i + 1) * D_DIM];
        float v2 = gp[(size_t)(i + 2) * D_DIM];
        float v3 = gp[(size_t)(i + 3) * D_DIM];
        float v4 = gp[(size_t)(i + 4) * D_DIM];
        float v5 = gp[(size_t)(i + 5) * D_DIM];
        float v6 = gp[(size_t)(i + 6) * D_DIM];
        float v7 = gp[(size_t)(i + 7) * D_DIM];
        rmw2(acc, p0  * D_DIM + tid, p1  * D_DIM + tid, v0);
        rmw2(acc, p2  * D_DIM + tid, p3  * D_DIM + tid, v1);
        rmw2(acc, p4  * D_DIM + tid, p5  * D_DIM + tid, v2);
        rmw2(acc, p6  * D_DIM + tid, p7  * D_DIM + tid, v3);
        rmw2(acc, p8  * D_DIM + tid, p9  * D_DIM + tid, v4);
        rmw2(acc, p10 * D_DIM + tid, p11 * D_DIM + tid, v5);
        rmw2(acc, p12 * D_DIM + tid, p13 * D_DIM + tid, v6);
        rmw2(acc, p14 * D_DIM + tid, p15 * D_DIM + tid, v7);
    }
    for (; i < n; ++i) {                   // dead for chunk%8==0, kept for safety
        int pa = tpp[2*i + 0], pb = tpp[2*i + 1];
        float v = gp[(size_t)i * D_DIM];
        rmw2(acc, pa * D_DIM + tid, pb * D_DIM + tid, v);
    }
    __syncthreads();

    if (use_atomic) {
        for (int j = tid; j < XSZ; j += THREADS1) {
            float v = acc[j];
            if (v != 0.0f) atomicAdd(&dst[j], v);
        }
    } else {
        // Plain coalesced float4 stores of this block's partial.
        f32x4* outp = (f32x4*)(dst + (size_t)blockIdx.x * XSZ);
        const f32x4* a4 = (const f32x4*)acc;
        for (int j = tid; j < XSZ / 4; j += THREADS1) outp[j] = a4[j];
    }
}

// ---------------------------------------------------------------------------
// Reduce 256 per-block partials -> x [B, D]. 33.5 MB of reads from L2/L3.
// 256 blocks x 128 threads = 2 waves/CU: latency-bound, so unroll 16 to
// double the loads in flight (~8 -> ~16 outstanding per thread).
// ---------------------------------------------------------------------------
__global__ __launch_bounds__(128)
void reduce_partials(const float* __restrict__ p, float* __restrict__ x) {
    int j = blockIdx.x * 128 + threadIdx.x;     // 0..32767
    const float* pj = p + j;
    float s = 0.0f;
    #pragma unroll 16
    for (int k = 0; k < NBLK1; ++k) s += pj[(size_t)k * XSZ];
    x[j] = s;
}

// ---------------------------------------------------------------------------
// Phase 2: broadcast x [B, D] -> out [B, L, D]. Each wave owns one contiguous
// 64 KB span (32 l-rows of one b) and streams sequential 1 KB wave-stores.
// 1024 blocks x 4 waves = 4096 spans. At the 6.6 TB/s write ceiling already.
// ---------------------------------------------------------------------------
#define BC_BLOCKS  1024
#define BC_THREADS 256
__global__ __launch_bounds__(BC_THREADS)
void bcast_lin(const float* __restrict__ x, f32x4* __restrict__ out) {
    int gw   = (blockIdx.x * BC_THREADS + threadIdx.x) >> 6;  // global wave 0..4095
    int lane = threadIdx.x & 63;
    size_t base = (size_t)gw * 4096;          // float4 units; span = 64 KB
    int b = (int)(base >> 18);                // 2^18 float4s per b

    const f32x4* x4 = (const f32x4*)x;
    f32x4 v0 = x4[(b << 7) | lane];
    f32x4 v1 = x4[(b << 7) | (64 + lane)];

    f32x4* o = out + base + lane;
    #pragma unroll 8
    for (int t = 0; t < 64; t += 2) {
        __builtin_nontemporal_store(v0, &o[(size_t)t * 64]);
        __builtin_nontemporal_store(v1, &o[(size_t)t * 64 + 64]);
    }
}

extern "C" void kernel_launch(void* const* d_in, const int* in_sizes, int n_in,
                              void* d_out, int out_size, void* d_ws, size_t ws_size,
                              hipStream_t stream) {
    const float* g   = (const float*)d_in[0];
    const int*   tp  = (const int*)d_in[1];
    float*       out = (float*)d_out;

    int N = in_sizes[1] / 2;               // 100000
    // Round chunk to a multiple of 8: tpp stays 64 B-aligned for x16 scalar
    // loads and every block's n is a multiple of 8 (392*255 + 40 = 100000).
    int chunk = (((N + NBLK1 - 1) / NBLK1) + 7) & ~7;   // 392

    const size_t need = (size_t)(NBLK1 + 1) * XSZ * sizeof(float);  // 33.7 MB

    if (ws_size >= need) {
        float* partials = (float*)d_ws;                    // [256][32768]
        float* x        = partials + (size_t)NBLK1 * XSZ;  // [64][512]
        seg_sum_kernel<<<NBLK1, THREADS1, 0, stream>>>(g, tp, partials, N, chunk, 0);
        reduce_partials<<<XSZ / 128, 128, 0, stream>>>(partials, x);
        bcast_lin<<<BC_BLOCKS, BC_THREADS, 0, stream>>>(x, (f32x4*)out);
    } else {
        // Fallback: atomic flush into x (d_ws poisoned 0xAA -> zero it first).
        float* x = (float*)d_ws;
        (void)hipMemsetAsync(d_ws, 0, XSZ * sizeof(float), stream);
        seg_sum_kernel<<<NBLK1, THREADS1, 0, stream>>>(g, tp, x, N, chunk, 1);
        bcast_lin<<<BC_BLOCKS, BC_THREADS, 0, stream>>>(x, (f32x4*)out);
    }
}